// Round 6
// baseline (89.893 us; speedup 1.0000x reference)
//
#include <hip/hip_runtime.h>
#include <math.h>

// Histogram2D as i8 MFMA GEMM: hist[i][j] = sum_n wx[n][i]*wy[n][j].
// q = rint(w*320) (max 123 < 127), exact i32 accumulation; 8-bin window
// (further bins < 0.5 quant LSB). ~42us of dur is the harness 0xAA poison
// of the 256MiB d_ws (fixed floor outside our control).
// R5 lessons: 16 waves/CU (VGPR=88 cap) fixed most latency; remaining
// slack is per-chunk barriers + partial traffic. R6: bf16 partials
// (halve traffic), single fused reduce using exact i32 btot for the
// normalizer, prefetch next x + compute next erf during MFMA phase.

#define NBINS   128
#define NB2     (NBINS * NBINS)
#define KC      256               // points per chunk
#define AX_B    32768             // bytes per axis staging: 128*256
#define THREADS 512
#define NBLOCKS 512               // 2 blocks/CU (64 KiB LDS each)
#define QSCALE  320.0f

typedef int i32x4 __attribute__((ext_vector_type(4)));

static __device__ __forceinline__ unsigned short f2bf(float f) {
    unsigned int b = __float_as_uint(f);
    b += 0x7fff + ((b >> 16) & 1);            // RNE
    return (unsigned short)(b >> 16);
}
static __device__ __forceinline__ float bf2f(unsigned short u) {
    return __uint_as_float((unsigned int)u << 16);
}

__global__ __launch_bounds__(THREADS, 4) void hist_mfma_kernel(
    const float* __restrict__ x,
    const float* __restrict__ edges_x,
    const float* __restrict__ edges_y,
    unsigned short* __restrict__ partials,   // bf16 [block][16384]
    float* __restrict__ btot,
    int n)
{
    // Staging element (bin b, point p), per axis:
    //   off = (b>>4)*4096 + (p>>6)*1024 + ((p>>4)&3)*256 + (b&15)*16 + (p&15)
    // Frag read (tile t, kstep s, lane l): t*4096 + s*1024 + l*16 ->
    // 16 contiguous bytes/lane, conflict-free (verified R3-R5).
    __shared__ __align__(16) signed char sh[2 * AX_B];   // 64 KiB
    __shared__ int xw[8];

    const int tid  = threadIdx.x;
    const int lane = tid & 63;
    const int wv   = tid >> 6;        // 0..7

    const float e0x = edges_x[0];
    const float dxw = edges_x[1] - e0x;
    const float e0y = edges_y[0];
    const float dyw = edges_y[1] - e0y;

    // scatter role: threads 0..255 axis x, 256..511 axis y, point = pl
    const int axis = tid >> 8;
    const int pl   = tid & 255;
    const float e0   = axis ? e0y : e0x;
    const float invd = 1.0f / (axis ? dyw : dxw);
    const float cc   = 0.7071067811865476f;   // 1/sqrt(2); bw = bin width
    signed char* const sdst =
        sh + axis * AX_B + (pl >> 6) * 1024 + ((pl >> 4) & 3) * 256 + (pl & 15);

    i32x4 acc[4][4];
    #pragma unroll
    for (int i = 0; i < 4; ++i)
        #pragma unroll
        for (int j = 0; j < 4; ++j)
            acc[i][j] = (i32x4){0, 0, 0, 0};

    const int rowQ = ((wv >> 1) & 1) * 4;  // 4x4 tile quadrant (16x16 tiles)
    const int colQ = (wv & 1) * 4;
    const int ks0  = (wv >> 2) * 2;        // K-split: waves 0-3 ksteps {0,1}, 4-7 {2,3}

    const int nchunks = (n + KC - 1) / KC;

    // preload chunk 0 and compute its q-bytes
    float u = 1e30f;
    {
        const int p = blockIdx.x * KC + pl;
        if (blockIdx.x < nchunks && p < n) u = x[(size_t)p * 6 + axis];
    }
    int b0;
    signed char qv[8];
    {
        const float spos = (u - e0) * invd;
        int b = (int)floorf(spos + 0.5f) - 4;
        b0 = b < 0 ? 0 : (b > NBINS - 8 ? NBINS - 8 : b);
        const float t0 = ((float)b0 - spos) * cc;
        float z[9];
        #pragma unroll
        for (int k = 0; k < 9; ++k) z[k] = erff(t0 + (float)k * cc);
        #pragma unroll
        for (int k = 0; k < 8; ++k)
            qv[k] = (signed char)(int)rintf(0.5f * (z[k + 1] - z[k]) * QSCALE);
    }

    for (int chunk = blockIdx.x; chunk < nchunks; chunk += gridDim.x) {
        // prefetch next chunk's coordinate (hide HBM latency)
        const int nchunk = chunk + gridDim.x;
        float un = 1e30f;
        if (nchunk < nchunks) {
            const int pn = nchunk * KC + pl;
            if (pn < n) un = x[(size_t)pn * 6 + axis];
        }

        // zero staging: 512 thr x 8 float4
        float4* zp = (float4*)sh;
        #pragma unroll
        for (int i = 0; i < 8; ++i)
            zp[tid + i * THREADS] = (float4){0.f, 0.f, 0.f, 0.f};
        __syncthreads();

        #pragma unroll
        for (int k = 0; k < 8; ++k) {
            const int b = b0 + k;
            sdst[(b >> 4) * 4096 + (b & 15) * 16] = qv[k];
        }
        __syncthreads();

        // MFMA phase; next chunk's erf/q interleaves on the VALU pipe
        #pragma unroll
        for (int s = 0; s < 2; ++s) {
            const int ks = ks0 + s;
            i32x4 av[4], bv[4];
            #pragma unroll
            for (int i = 0; i < 4; ++i)
                av[i] = *(const i32x4*)(sh + (rowQ + i) * 4096 + ks * 1024 + lane * 16);
            #pragma unroll
            for (int j = 0; j < 4; ++j)
                bv[j] = *(const i32x4*)(sh + AX_B + (colQ + j) * 4096 + ks * 1024 + lane * 16);
            #pragma unroll
            for (int i = 0; i < 4; ++i)
                #pragma unroll
                for (int j = 0; j < 4; ++j)
                    acc[i][j] = __builtin_amdgcn_mfma_i32_16x16x64_i8(
                        av[i], bv[j], acc[i][j], 0, 0, 0);
        }

        {   // compute next chunk's q-bytes (overlaps MFMA/ds_read latency)
            const float spos = (un - e0) * invd;
            int b = (int)floorf(spos + 0.5f) - 4;
            b0 = b < 0 ? 0 : (b > NBINS - 8 ? NBINS - 8 : b);
            const float t0 = ((float)b0 - spos) * cc;
            float z[9];
            #pragma unroll
            for (int k = 0; k < 9; ++k) z[k] = erff(t0 + (float)k * cc);
            #pragma unroll
            for (int k = 0; k < 8; ++k)
                qv[k] = (signed char)(int)rintf(0.5f * (z[k + 1] - z[k]) * QSCALE);
        }
        __syncthreads();
    }

    // epilogue: merge K-split wave pairs (exact i32), then scale & store bf16.
    // C/D layout col=lane&15, row=(lane>>4)*4+reg (shape-determined).
    if (wv >= 4) {
        int* dst = (int*)sh + (wv - 4) * 4096;
        #pragma unroll
        for (int i = 0; i < 4; ++i)
            #pragma unroll
            for (int j = 0; j < 4; ++j)
                #pragma unroll
                for (int g = 0; g < 4; ++g)
                    dst[((i * 4 + j) * 4 + g) * 64 + lane] = acc[i][j][g];
    }
    __syncthreads();

    int bsum = 0;
    if (wv < 4) {
        const float qs = 1.0f / (QSCALE * QSCALE);
        const int* src = (const int*)sh + wv * 4096;
        unsigned short* my = partials + (size_t)blockIdx.x * NB2;
        const int r0 = (lane >> 4) * 4;
        const int c0 = lane & 15;
        #pragma unroll
        for (int i = 0; i < 4; ++i)
            #pragma unroll
            for (int j = 0; j < 4; ++j)
                #pragma unroll
                for (int g = 0; g < 4; ++g) {
                    const int v = acc[i][j][g] + src[((i * 4 + j) * 4 + g) * 64 + lane];
                    bsum += v;
                    const int row = (rowQ + i) * 16 + r0 + g;
                    const int col = (colQ + j) * 16 + c0;
                    my[row * NBINS + col] = f2bf((float)v * qs);
                }
    }
    // block total (exact i32 within wave)
    #pragma unroll
    for (int off = 32; off > 0; off >>= 1) bsum += __shfl_down(bsum, off, 64);
    if (lane == 0) xw[wv] = bsum;
    __syncthreads();
    if (tid == 0) {
        const float qs = 1.0f / (QSCALE * QSCALE);
        btot[blockIdx.x] = (float)(xw[0] + xw[1] + xw[2] + xw[3]) * qs;
    }
}

// Fused reduction + normalize: 128 blocks x 256 threads.
// Block B covers bins [B*128, B*128+128). Thread t: bin4 = t&31 (4 bins),
// pgroup = t>>5 (64 partials each). Sums bf16 partials; normalizer from btot.
__global__ void reduce_kernel(const unsigned short* __restrict__ partials,
                              const float* __restrict__ btot,
                              const float* __restrict__ edges_x,
                              const float* __restrict__ edges_y,
                              float* __restrict__ out)
{
    __shared__ float4 red[8][32];
    __shared__ float ws[4];
    __shared__ float stot;

    const int t = threadIdx.x;
    const int bin4 = t & 31;
    const int pg = t >> 5;
    const int binBase = blockIdx.x * 128;

    // grand total (redundant per block; btot is 2KB, L2-hot)
    float tl = btot[t] + btot[t + 256];
    #pragma unroll
    for (int off = 32; off > 0; off >>= 1) tl += __shfl_down(tl, off, 64);
    if ((t & 63) == 0) ws[t >> 6] = tl;

    // sum 64 partials for 4 bins
    const unsigned short* p =
        partials + (size_t)(pg * 64) * NB2 + binBase + bin4 * 4;
    float4 s = {0.f, 0.f, 0.f, 0.f};
    #pragma unroll 8
    for (int k = 0; k < 64; ++k) {
        const ushort4 v = *(const ushort4*)(p + (size_t)k * NB2);
        s.x += bf2f(v.x); s.y += bf2f(v.y); s.z += bf2f(v.z); s.w += bf2f(v.w);
    }
    red[pg][bin4] = s;
    __syncthreads();

    if (t == 0) {
        const float dxw = edges_x[1] - edges_x[0];
        const float dyw = edges_y[1] - edges_y[0];
        stot = 1.0f / ((ws[0] + ws[1] + ws[2] + ws[3]) * dxw * dyw);
    }
    __syncthreads();

    if (t < 32) {
        float4 a = red[0][t];
        #pragma unroll
        for (int g = 1; g < 8; ++g) {
            const float4 b = red[g][t];
            a.x += b.x; a.y += b.y; a.z += b.z; a.w += b.w;
        }
        a.x *= stot; a.y *= stot; a.z *= stot; a.w *= stot;
        *(float4*)(out + binBase + t * 4) = a;
    }
}

extern "C" void kernel_launch(void* const* d_in, const int* in_sizes, int n_in,
                              void* d_out, int out_size, void* d_ws, size_t ws_size,
                              hipStream_t stream)
{
    const float* x  = (const float*)d_in[0];
    const float* ex = (const float*)d_in[1];
    const float* ey = (const float*)d_in[2];
    float* out = (float*)d_out;
    const int n = in_sizes[0] / 6;

    unsigned short* partials = (unsigned short*)d_ws;         // 512*16384 bf16
    float* btot = (float*)((char*)d_ws + (size_t)NBLOCKS * NB2 * 2);  // 512 f32

    hist_mfma_kernel<<<NBLOCKS, THREADS, 0, stream>>>(x, ex, ey, partials, btot, n);
    reduce_kernel<<<NB2 / 128, 256, 0, stream>>>(partials, btot, ex, ey, out);
}

// Round 7
// 86.112 us; speedup vs baseline: 1.0439x; 1.0439x over previous
//
#include <hip/hip_runtime.h>
#include <math.h>

// Histogram2D as i8 MFMA GEMM: hist[i][j] = sum_n wx[n][i]*wy[n][j].
// q = rint(w*320) (max 123 < 127), exact i32 accumulation; 8-bin window
// (further bins < 0.5 quant LSB). ~42us of dur is the harness 0xAA poison
// of the 256MiB d_ws (fixed floor outside our control).
// R6 lesson: tail-kernel traffic cuts were neutral -> hist dominates at
// ~35us vs ~8us LDS-busy model; libm erff (~80 branchy instrs, both
// divergent paths execute) is the largest reducible term.
// R7: branch-free A&S 7.1.26 erf (rcp + exp + 8 fma, |eps|<=1.5e-7,
// << quant LSB 1/640). Single-variable change vs R6.

#define NBINS   128
#define NB2     (NBINS * NBINS)
#define KC      256               // points per chunk
#define AX_B    32768             // bytes per axis staging: 128*256
#define THREADS 512
#define NBLOCKS 512               // 2 blocks/CU (64 KiB LDS each)
#define QSCALE  320.0f

typedef int i32x4 __attribute__((ext_vector_type(4)));

static __device__ __forceinline__ unsigned short f2bf(float f) {
    unsigned int b = __float_as_uint(f);
    b += 0x7fff + ((b >> 16) & 1);            // RNE
    return (unsigned short)(b >> 16);
}
static __device__ __forceinline__ float bf2f(unsigned short u) {
    return __uint_as_float((unsigned int)u << 16);
}

// Abramowitz-Stegun 7.1.26: |err| <= 1.5e-7, branch-free.
// erf(x) = sign(x) * (1 - (a1 t + .. + a5 t^5) exp(-x^2)), t = 1/(1+p|x|)
static __device__ __forceinline__ float erf_fast(float x) {
    const float ax = fabsf(x);
    const float t  = __builtin_amdgcn_rcpf(fmaf(0.3275911f, ax, 1.0f));
    const float e  = __expf(-x * x);          // v_exp_f32; inf^2 -> e=0 safe
    float p = fmaf(1.061405429f, t, -1.453152027f);
    p = fmaf(p, t, 1.421413741f);
    p = fmaf(p, t, -0.284496736f);
    p = fmaf(p, t, 0.254829592f);
    p = p * t;
    return copysignf(fmaf(-p, e, 1.0f), x);
}

__global__ __launch_bounds__(THREADS, 4) void hist_mfma_kernel(
    const float* __restrict__ x,
    const float* __restrict__ edges_x,
    const float* __restrict__ edges_y,
    unsigned short* __restrict__ partials,   // bf16 [block][16384]
    float* __restrict__ btot,
    int n)
{
    // Staging element (bin b, point p), per axis:
    //   off = (b>>4)*4096 + (p>>6)*1024 + ((p>>4)&3)*256 + (b&15)*16 + (p&15)
    // Frag read (tile t, kstep s, lane l): t*4096 + s*1024 + l*16 ->
    // 16 contiguous bytes/lane, conflict-free (verified R3-R6).
    __shared__ __align__(16) signed char sh[2 * AX_B];   // 64 KiB
    __shared__ int xw[8];

    const int tid  = threadIdx.x;
    const int lane = tid & 63;
    const int wv   = tid >> 6;        // 0..7

    const float e0x = edges_x[0];
    const float dxw = edges_x[1] - e0x;
    const float e0y = edges_y[0];
    const float dyw = edges_y[1] - e0y;

    // scatter role: threads 0..255 axis x, 256..511 axis y, point = pl
    const int axis = tid >> 8;
    const int pl   = tid & 255;
    const float e0   = axis ? e0y : e0x;
    const float invd = 1.0f / (axis ? dyw : dxw);
    const float cc   = 0.7071067811865476f;   // 1/sqrt(2); bw = bin width
    signed char* const sdst =
        sh + axis * AX_B + (pl >> 6) * 1024 + ((pl >> 4) & 3) * 256 + (pl & 15);

    i32x4 acc[4][4];
    #pragma unroll
    for (int i = 0; i < 4; ++i)
        #pragma unroll
        for (int j = 0; j < 4; ++j)
            acc[i][j] = (i32x4){0, 0, 0, 0};

    const int rowQ = ((wv >> 1) & 1) * 4;  // 4x4 tile quadrant (16x16 tiles)
    const int colQ = (wv & 1) * 4;
    const int ks0  = (wv >> 2) * 2;        // K-split: waves 0-3 ksteps {0,1}, 4-7 {2,3}

    const int nchunks = (n + KC - 1) / KC;

    // preload chunk 0 and compute its q-bytes
    float u = 1e30f;
    {
        const int p = blockIdx.x * KC + pl;
        if (blockIdx.x < nchunks && p < n) u = x[(size_t)p * 6 + axis];
    }
    int b0;
    signed char qv[8];
    {
        const float spos = (u - e0) * invd;
        int b = (int)floorf(spos + 0.5f) - 4;
        b0 = b < 0 ? 0 : (b > NBINS - 8 ? NBINS - 8 : b);
        const float t0 = ((float)b0 - spos) * cc;
        float z[9];
        #pragma unroll
        for (int k = 0; k < 9; ++k) z[k] = erf_fast(t0 + (float)k * cc);
        #pragma unroll
        for (int k = 0; k < 8; ++k)
            qv[k] = (signed char)(int)rintf(0.5f * (z[k + 1] - z[k]) * QSCALE);
    }

    for (int chunk = blockIdx.x; chunk < nchunks; chunk += gridDim.x) {
        // prefetch next chunk's coordinate (hide HBM latency)
        const int nchunk = chunk + gridDim.x;
        float un = 1e30f;
        if (nchunk < nchunks) {
            const int pn = nchunk * KC + pl;
            if (pn < n) un = x[(size_t)pn * 6 + axis];
        }

        // zero staging: 512 thr x 8 float4
        float4* zp = (float4*)sh;
        #pragma unroll
        for (int i = 0; i < 8; ++i)
            zp[tid + i * THREADS] = (float4){0.f, 0.f, 0.f, 0.f};
        __syncthreads();

        #pragma unroll
        for (int k = 0; k < 8; ++k) {
            const int b = b0 + k;
            sdst[(b >> 4) * 4096 + (b & 15) * 16] = qv[k];
        }
        __syncthreads();

        // MFMA phase; next chunk's erf/q interleaves on the VALU pipe
        #pragma unroll
        for (int s = 0; s < 2; ++s) {
            const int ks = ks0 + s;
            i32x4 av[4], bv[4];
            #pragma unroll
            for (int i = 0; i < 4; ++i)
                av[i] = *(const i32x4*)(sh + (rowQ + i) * 4096 + ks * 1024 + lane * 16);
            #pragma unroll
            for (int j = 0; j < 4; ++j)
                bv[j] = *(const i32x4*)(sh + AX_B + (colQ + j) * 4096 + ks * 1024 + lane * 16);
            #pragma unroll
            for (int i = 0; i < 4; ++i)
                #pragma unroll
                for (int j = 0; j < 4; ++j)
                    acc[i][j] = __builtin_amdgcn_mfma_i32_16x16x64_i8(
                        av[i], bv[j], acc[i][j], 0, 0, 0);
        }

        {   // compute next chunk's q-bytes (overlaps MFMA/ds_read latency)
            const float spos = (un - e0) * invd;
            int b = (int)floorf(spos + 0.5f) - 4;
            b0 = b < 0 ? 0 : (b > NBINS - 8 ? NBINS - 8 : b);
            const float t0 = ((float)b0 - spos) * cc;
            float z[9];
            #pragma unroll
            for (int k = 0; k < 9; ++k) z[k] = erf_fast(t0 + (float)k * cc);
            #pragma unroll
            for (int k = 0; k < 8; ++k)
                qv[k] = (signed char)(int)rintf(0.5f * (z[k + 1] - z[k]) * QSCALE);
        }
        __syncthreads();
    }

    // epilogue: merge K-split wave pairs (exact i32), then scale & store bf16.
    // C/D layout col=lane&15, row=(lane>>4)*4+reg (shape-determined).
    if (wv >= 4) {
        int* dst = (int*)sh + (wv - 4) * 4096;
        #pragma unroll
        for (int i = 0; i < 4; ++i)
            #pragma unroll
            for (int j = 0; j < 4; ++j)
                #pragma unroll
                for (int g = 0; g < 4; ++g)
                    dst[((i * 4 + j) * 4 + g) * 64 + lane] = acc[i][j][g];
    }
    __syncthreads();

    int bsum = 0;
    if (wv < 4) {
        const float qs = 1.0f / (QSCALE * QSCALE);
        const int* src = (const int*)sh + wv * 4096;
        unsigned short* my = partials + (size_t)blockIdx.x * NB2;
        const int r0 = (lane >> 4) * 4;
        const int c0 = lane & 15;
        #pragma unroll
        for (int i = 0; i < 4; ++i)
            #pragma unroll
            for (int j = 0; j < 4; ++j)
                #pragma unroll
                for (int g = 0; g < 4; ++g) {
                    const int v = acc[i][j][g] + src[((i * 4 + j) * 4 + g) * 64 + lane];
                    bsum += v;
                    const int row = (rowQ + i) * 16 + r0 + g;
                    const int col = (colQ + j) * 16 + c0;
                    my[row * NBINS + col] = f2bf((float)v * qs);
                }
    }
    // block total (exact i32 within wave)
    #pragma unroll
    for (int off = 32; off > 0; off >>= 1) bsum += __shfl_down(bsum, off, 64);
    if (lane == 0) xw[wv] = bsum;
    __syncthreads();
    if (tid == 0) {
        const float qs = 1.0f / (QSCALE * QSCALE);
        btot[blockIdx.x] = (float)(xw[0] + xw[1] + xw[2] + xw[3]) * qs;
    }
}

// Fused reduction + normalize: 128 blocks x 256 threads.
// Block B covers bins [B*128, B*128+128). Thread t: bin4 = t&31 (4 bins),
// pgroup = t>>5 (64 partials each). Sums bf16 partials; normalizer from btot.
__global__ void reduce_kernel(const unsigned short* __restrict__ partials,
                              const float* __restrict__ btot,
                              const float* __restrict__ edges_x,
                              const float* __restrict__ edges_y,
                              float* __restrict__ out)
{
    __shared__ float4 red[8][32];
    __shared__ float ws[4];
    __shared__ float stot;

    const int t = threadIdx.x;
    const int bin4 = t & 31;
    const int pg = t >> 5;
    const int binBase = blockIdx.x * 128;

    // grand total (redundant per block; btot is 2KB, L2-hot)
    float tl = btot[t] + btot[t + 256];
    #pragma unroll
    for (int off = 32; off > 0; off >>= 1) tl += __shfl_down(tl, off, 64);
    if ((t & 63) == 0) ws[t >> 6] = tl;

    // sum 64 partials for 4 bins
    const unsigned short* p =
        partials + (size_t)(pg * 64) * NB2 + binBase + bin4 * 4;
    float4 s = {0.f, 0.f, 0.f, 0.f};
    #pragma unroll 8
    for (int k = 0; k < 64; ++k) {
        const ushort4 v = *(const ushort4*)(p + (size_t)k * NB2);
        s.x += bf2f(v.x); s.y += bf2f(v.y); s.z += bf2f(v.z); s.w += bf2f(v.w);
    }
    red[pg][bin4] = s;
    __syncthreads();

    if (t == 0) {
        const float dxw = edges_x[1] - edges_x[0];
        const float dyw = edges_y[1] - edges_y[0];
        stot = 1.0f / ((ws[0] + ws[1] + ws[2] + ws[3]) * dxw * dyw);
    }
    __syncthreads();

    if (t < 32) {
        float4 a = red[0][t];
        #pragma unroll
        for (int g = 1; g < 8; ++g) {
            const float4 b = red[g][t];
            a.x += b.x; a.y += b.y; a.z += b.z; a.w += b.w;
        }
        a.x *= stot; a.y *= stot; a.z *= stot; a.w *= stot;
        *(float4*)(out + binBase + t * 4) = a;
    }
}

extern "C" void kernel_launch(void* const* d_in, const int* in_sizes, int n_in,
                              void* d_out, int out_size, void* d_ws, size_t ws_size,
                              hipStream_t stream)
{
    const float* x  = (const float*)d_in[0];
    const float* ex = (const float*)d_in[1];
    const float* ey = (const float*)d_in[2];
    float* out = (float*)d_out;
    const int n = in_sizes[0] / 6;

    unsigned short* partials = (unsigned short*)d_ws;         // 512*16384 bf16
    float* btot = (float*)((char*)d_ws + (size_t)NBLOCKS * NB2 * 2);  // 512 f32

    hist_mfma_kernel<<<NBLOCKS, THREADS, 0, stream>>>(x, ex, ey, partials, btot, n);
    reduce_kernel<<<NB2 / 128, 256, 0, stream>>>(partials, btot, ex, ey, out);
}